// Round 13
// baseline (472.858 us; speedup 1.0000x reference)
//
#include <hip/hip_runtime.h>
#include <hip/hip_bf16.h>

#define L_SEQ 1024
#define CCH   512
#define NB    8
#define NROW  (NB * L_SEQ)

typedef __bf16 bf16_t;
typedef __bf16 bf16x4 __attribute__((ext_vector_type(4)));
typedef __bf16 bf16x8 __attribute__((ext_vector_type(8)));
typedef float  f32x4  __attribute__((ext_vector_type(4)));

__device__ __forceinline__ void gload_lds16(const void* g, void* l) {
  __builtin_amdgcn_global_load_lds((const __attribute__((address_space(1))) void*)g,
                                   (__attribute__((address_space(3))) void*)l, 16, 0, 0);
}

// ======== prep: PE+transpose (+LN partials, bf16 OUT) AND weight conversions ========
__global__ __launch_bounds__(256) void prep_kernel(
    const float* __restrict__ x,
    const float* __restrict__ pw_w, const float* __restrict__ Wq,
    const float* __restrict__ Wk, const float* __restrict__ Wv,
    const float* __restrict__ Wo, const float* __restrict__ Wf,
    const float* __restrict__ dw_w,
    bf16_t* __restrict__ WPW, bf16_t* __restrict__ WQKV,
    bf16_t* __restrict__ WOB, bf16_t* __restrict__ WFB,
    float* __restrict__ WT,
    bf16_t* __restrict__ out, float* __restrict__ Psum, float* __restrict__ Psq) {
  int blk = blockIdx.x;
  if (blk < 4096) {
    __shared__ float tile[32][33];
    int bx = blk & 31, by = (blk >> 5) & 15, b = blk >> 9;
    int l0 = bx * 32, c0 = by * 32;
    int tx = threadIdx.x & 31, ty = threadIdx.x >> 5;
#pragma unroll
    for (int r = 0; r < 32; r += 8)
      tile[ty + r][tx] = x[(size_t)(b * CCH + c0 + ty + r) * L_SEQ + l0 + tx];
    __syncthreads();
#pragma unroll
    for (int r = 0; r < 32; r += 8) {
      int l = l0 + ty + r, c = c0 + tx;
      float div = expf(-(float)(2 * (c >> 1)) * (9.210340371976184f / 512.0f));
      float ang = (float)l * div;
      float pe = (c & 1) ? cosf(ang) : sinf(ang);
      float v = tile[tx][ty + r] + pe;
      out[(size_t)(b * L_SEQ + l) * CCH + c] = (bf16_t)v;
      float s = v, q = v * v;
#pragma unroll
      for (int off = 1; off < 32; off <<= 1) {
        s += __shfl_xor(s, off);
        q += __shfl_xor(q, off);
      }
      if (tx == 0) {
        size_t row = (size_t)(b * L_SEQ + l);
        Psum[row * 16 + (c0 >> 5)] = s;
        Psq[row * 16 + (c0 >> 5)] = q;
      }
    }
    return;
  }
  int idx = (blk - 4096) * 256 + threadIdx.x;
  if (idx < 1048576) { WPW[idx] = (bf16_t)pw_w[idx]; return; }
  idx -= 1048576;
  if (idx < 262144) { WQKV[idx] = (bf16_t)Wq[idx]; return; }
  idx -= 262144;
  if (idx < 262144) { WQKV[262144 + idx] = (bf16_t)Wk[idx]; return; }
  idx -= 262144;
  if (idx < 262144) { WQKV[524288 + idx] = (bf16_t)Wv[idx]; return; }
  idx -= 262144;
  if (idx < 262144) { WOB[idx] = (bf16_t)Wo[idx]; return; }
  idx -= 262144;
  if (idx < 262144) { WFB[idx] = (bf16_t)Wf[idx]; return; }
  idx -= 262144;
  if (idx < 14336) {
    int i = idx / 3584, r = idx % 3584, t = r >> 9, c = r & 511;
    WT[idx] = dw_w[i * 3584 + c * 7 + t];
  }
}

// ======== shared GEMM compute: BM=64 BN=128 BK=64 ========
#define GCOMP64(BI)                                                               \
  do {                                                                            \
    __builtin_amdgcn_s_setprio(1);                                                \
    _Pragma("unroll") for (int ks = 0; ks < 2; ks++) {                            \
      bf16x8 fa[2], fb[4];                                                        \
      _Pragma("unroll") for (int i = 0; i < 2; i++) {                             \
        int ra = wr * 32 + i * 16 + lc;                                           \
        fa[i] = *(const bf16x8*)&As[BI][ra * 64 +                                 \
                 (((ks * 64 + lg * 16) ^ ((ra & 7) << 4)) >> 1)];                 \
      }                                                                           \
      _Pragma("unroll") for (int j = 0; j < 4; j++) {                             \
        int rb = wc * 64 + j * 16 + lc;                                           \
        fb[j] = *(const bf16x8*)&Bs[BI][rb * 64 +                                 \
                 (((ks * 64 + lg * 16) ^ ((rb & 7) << 4)) >> 1)];                 \
      }                                                                           \
      _Pragma("unroll") for (int i = 0; i < 2; i++)                               \
        _Pragma("unroll") for (int j = 0; j < 4; j++)                             \
          acc[i][j] = __builtin_amdgcn_mfma_f32_16x16x32_bf16(fa[i], fb[j],       \
                                                              acc[i][j], 0, 0, 0);\
    }                                                                             \
    __builtin_amdgcn_s_setprio(0);                                                \
  } while (0)

#define BSTAGE128(SRCB, BI, K0)                                                   \
  _Pragma("unroll") for (int cc = 0; cc < 4; cc++) {                              \
    int row_ = cc * 32 + w * 8 + srow;                                            \
    int off_ = (scb ^ ((row_ & 7) << 4)) >> 1;                                    \
    gload_lds16(SRCB + (size_t)(n0 + row_) * CCH + (K0) + off_,                   \
                &Bs[BI][(cc * 32 + w * 8) * 64]);                                 \
  }

// ======== fused LN + depthwise-conv + pointwise GEMM (one conv stage) ========
// A-staging is reg-staged: load LINEAR column cl, write SWIZZLED slot csw
// (rule #21: value for global col cl must land at LDS byte cl^swz).
__global__ __launch_bounds__(256) void gemm_conv(
    const bf16_t* __restrict__ IN, const float* __restrict__ Psum,
    const float* __restrict__ Psq,
    const float* __restrict__ gam, const float* __restrict__ bet,
    const float* __restrict__ wtt, const float* __restrict__ dbias,
    const bf16_t* __restrict__ W, const float* __restrict__ bias,
    bf16_t* __restrict__ OUTn, float* __restrict__ PsumO,
    float* __restrict__ PsqO) {
  __shared__ __align__(16) bf16_t As[2][64 * 64];
  __shared__ __align__(16) bf16_t Bs[2][128 * 64];
  __shared__ float2 st[72];
  int tid = threadIdx.x;
  int w = tid >> 6, l = tid & 63;
  int m0 = blockIdx.x * 64, n0 = blockIdx.y * 128;
  int wr = w >> 1, wc = w & 1;
  int lc = l & 15, lg = l >> 4;
  int srow = l >> 3, scb = (l & 7) * 16;
  int cl = (l & 7) * 8;  // linear column (elements)

  if (tid < 70) {
    int gr = m0 - 3 + tid;
    float s = 0.f, q = 0.f;
    if (gr >= 0 && gr < NROW) {
#pragma unroll
      for (int c = 0; c < 16; c++) {
        s += Psum[(size_t)gr * 16 + c];
        q += Psq[(size_t)gr * 16 + c];
      }
    }
    float mean = s * (1.f / 512.f);
    float inv = rsqrtf(q * (1.f / 512.f) - mean * mean + 1e-5f);
    st[tid] = make_float2(mean, inv);
  }
  __syncthreads();

  int row0 = w * 8 + srow, row1 = row0 + 32;
  int csw = (scb ^ ((row0 & 7) << 4)) >> 1;  // swizzled LDS slot (elements)
  int gl0 = (m0 + row0) & (L_SEQ - 1);
  int gl1 = (m0 + row1) & (L_SEQ - 1);
  float2 mi0[7], mi1[7];
  bool v0[7], v1[7];
#pragma unroll
  for (int t = 0; t < 7; t++) {
    mi0[t] = st[row0 + t];
    mi1[t] = st[row1 + t];
    v0[t] = (unsigned)(gl0 + t - 3) < L_SEQ;
    v1[t] = (unsigned)(gl1 + t - 3) < L_SEQ;
  }

  bf16x8 hv0[7], hv1[7];
#define CONV_ALOAD(K0)                                                            \
  _Pragma("unroll") for (int t = 0; t < 7; t++) {                                 \
    int r0_ = m0 + row0 + t - 3; r0_ = r0_ < 0 ? 0 : (r0_ > NROW - 1 ? NROW - 1 : r0_); \
    int r1_ = m0 + row1 + t - 3; r1_ = r1_ < 0 ? 0 : (r1_ > NROW - 1 ? NROW - 1 : r1_); \
    hv0[t] = *(const bf16x8*)&IN[(size_t)r0_ * CCH + (K0) + cl];                  \
    hv1[t] = *(const bf16x8*)&IN[(size_t)r1_ * CCH + (K0) + cl];                  \
  }

#define CONV_AWRITE(BI, K0)                                                       \
  do {                                                                            \
    float gv[8], bv[8], a0[8], a1[8];                                             \
    *(float4*)&gv[0] = *(const float4*)(gam + (K0) + cl);                         \
    *(float4*)&gv[4] = *(const float4*)(gam + (K0) + cl + 4);                     \
    *(float4*)&bv[0] = *(const float4*)(bet + (K0) + cl);                         \
    *(float4*)&bv[4] = *(const float4*)(bet + (K0) + cl + 4);                     \
    *(float4*)&a0[0] = *(const float4*)(dbias + (K0) + cl);                       \
    *(float4*)&a0[4] = *(const float4*)(dbias + (K0) + cl + 4);                   \
    _Pragma("unroll") for (int j = 0; j < 8; j++) a1[j] = a0[j];                  \
    _Pragma("unroll") for (int t = 0; t < 7; t++) {                               \
      float wv[8];                                                                \
      *(float4*)&wv[0] = *(const float4*)(wtt + t * CCH + (K0) + cl);             \
      *(float4*)&wv[4] = *(const float4*)(wtt + t * CCH + (K0) + cl + 4);         \
      if (v0[t]) {                                                                \
        _Pragma("unroll") for (int j = 0; j < 8; j++)                             \
          a0[j] += (((float)hv0[t][j] - mi0[t].x) * mi0[t].y * gv[j] + bv[j]) * wv[j]; \
      }                                                                           \
      if (v1[t]) {                                                                \
        _Pragma("unroll") for (int j = 0; j < 8; j++)                             \
          a1[j] += (((float)hv1[t][j] - mi1[t].x) * mi1[t].y * gv[j] + bv[j]) * wv[j]; \
      }                                                                           \
    }                                                                             \
    bf16x8 o0, o1;                                                                \
    _Pragma("unroll") for (int j = 0; j < 8; j++) {                               \
      o0[j] = (bf16_t)a0[j]; o1[j] = (bf16_t)a1[j];                               \
    }                                                                             \
    *(bf16x8*)&As[BI][row0 * 64 + csw] = o0;                                      \
    *(bf16x8*)&As[BI][row1 * 64 + csw] = o1;                                      \
  } while (0)

  f32x4 acc[2][4];
#pragma unroll
  for (int i = 0; i < 2; i++)
#pragma unroll
    for (int j = 0; j < 4; j++) acc[i][j] = f32x4{0.f, 0.f, 0.f, 0.f};

  BSTAGE128(W, 0, 0);
  CONV_ALOAD(0);
  CONV_AWRITE(0, 0);
  __syncthreads();
  int cur = 0;
  for (int kk = 0; kk < 8; kk++) {
    if (kk < 7) { BSTAGE128(W, cur ^ 1, (kk + 1) * 64); CONV_ALOAD((kk + 1) * 64); }
    GCOMP64(cur);
    if (kk < 7) CONV_AWRITE(cur ^ 1, (kk + 1) * 64);
    __syncthreads();
    cur ^= 1;
  }

  // epilogue: bias + relu + residual(IN) -> OUTn (bf16) + LN partials
#pragma unroll
  for (int i = 0; i < 2; i++) {
    int mbase = m0 + wr * 32 + i * 16 + lg * 4;
    float ps[2][4], pq[2][4];
#pragma unroll
    for (int jh = 0; jh < 2; jh++)
#pragma unroll
      for (int r = 0; r < 4; r++) { ps[jh][r] = 0.f; pq[jh][r] = 0.f; }
#pragma unroll
    for (int j = 0; j < 4; j++) {
      int n = n0 + wc * 64 + j * 16 + lc;
      float bn = bias[n];
#pragma unroll
      for (int r = 0; r < 4; r++) {
        int m = mbase + r;
        float v2 = fmaxf(acc[i][j][r] + bn, 0.f) + (float)IN[(size_t)m * CCH + n];
        OUTn[(size_t)m * CCH + n] = (bf16_t)v2;
        ps[j >> 1][r] += v2;
        pq[j >> 1][r] += v2 * v2;
      }
    }
#pragma unroll
    for (int jh = 0; jh < 2; jh++)
#pragma unroll
      for (int r = 0; r < 4; r++) {
        float s = ps[jh][r], q = pq[jh][r];
        s += __shfl_xor(s, 1); q += __shfl_xor(q, 1);
        s += __shfl_xor(s, 2); q += __shfl_xor(q, 2);
        s += __shfl_xor(s, 4); q += __shfl_xor(q, 4);
        s += __shfl_xor(s, 8); q += __shfl_xor(q, 8);
        if (lc == 0) {
          size_t row = mbase + r;
          PsumO[row * 16 + blockIdx.y * 4 + wc * 2 + jh] = s;
          PsqO[row * 16 + blockIdx.y * 4 + wc * 2 + jh] = q;
        }
      }
  }
}

// ======== plain GEMM (Wo): BM=64 BN=128, bf16 res, bf16 out, stats ========
__global__ __launch_bounds__(256) void gemm_wo(const bf16_t* __restrict__ A,
                                               const bf16_t* __restrict__ W,
                                               const float* __restrict__ bias,
                                               const bf16_t* __restrict__ res,
                                               bf16_t* __restrict__ outb,
                                               float* __restrict__ PsumO,
                                               float* __restrict__ PsqO) {
  __shared__ __align__(16) bf16_t As[2][64 * 64];
  __shared__ __align__(16) bf16_t Bs[2][128 * 64];
  int tid = threadIdx.x;
  int w = tid >> 6, l = tid & 63;
  int m0 = blockIdx.x * 64, n0 = blockIdx.y * 128;
  int wr = w >> 1, wc = w & 1;
  int lc = l & 15, lg = l >> 4;
  int srow = l >> 3, scb = (l & 7) * 16;
  f32x4 acc[2][4];
#pragma unroll
  for (int i = 0; i < 2; i++)
#pragma unroll
    for (int j = 0; j < 4; j++) acc[i][j] = f32x4{0.f, 0.f, 0.f, 0.f};

#define WO_ASTAGE(BI, K0)                                                         \
  _Pragma("unroll") for (int cc = 0; cc < 2; cc++) {                              \
    int row_ = cc * 32 + w * 8 + srow;                                            \
    int off_ = (scb ^ ((row_ & 7) << 4)) >> 1;                                    \
    gload_lds16(A + (size_t)(m0 + row_) * CCH + (K0) + off_,                      \
                &As[BI][(cc * 32 + w * 8) * 64]);                                 \
  }

  WO_ASTAGE(0, 0);
  BSTAGE128(W, 0, 0);
  __syncthreads();
  int cur = 0;
  for (int kk = 0; kk < 8; kk++) {
    if (kk < 7) { WO_ASTAGE(cur ^ 1, (kk + 1) * 64); BSTAGE128(W, cur ^ 1, (kk + 1) * 64); }
    GCOMP64(cur);
    __syncthreads();
    cur ^= 1;
  }

#pragma unroll
  for (int i = 0; i < 2; i++) {
    int mbase = m0 + wr * 32 + i * 16 + lg * 4;
    float ps[2][4], pq[2][4];
#pragma unroll
    for (int jh = 0; jh < 2; jh++)
#pragma unroll
      for (int r = 0; r < 4; r++) { ps[jh][r] = 0.f; pq[jh][r] = 0.f; }
#pragma unroll
    for (int j = 0; j < 4; j++) {
      int n = n0 + wc * 64 + j * 16 + lc;
      float bn = bias[n];
#pragma unroll
      for (int r = 0; r < 4; r++) {
        int m = mbase + r;
        float v2 = acc[i][j][r] + bn + (float)res[(size_t)m * CCH + n];
        outb[(size_t)m * CCH + n] = (bf16_t)v2;
        ps[j >> 1][r] += v2;
        pq[j >> 1][r] += v2 * v2;
      }
    }
#pragma unroll
    for (int jh = 0; jh < 2; jh++)
#pragma unroll
      for (int r = 0; r < 4; r++) {
        float s = ps[jh][r], q = pq[jh][r];
        s += __shfl_xor(s, 1); q += __shfl_xor(q, 1);
        s += __shfl_xor(s, 2); q += __shfl_xor(q, 2);
        s += __shfl_xor(s, 4); q += __shfl_xor(q, 4);
        s += __shfl_xor(s, 8); q += __shfl_xor(q, 8);
        if (lc == 0) {
          size_t row = mbase + r;
          PsumO[row * 16 + blockIdx.y * 4 + wc * 2 + jh] = s;
          PsqO[row * 16 + blockIdx.y * 4 + wc * 2 + jh] = q;
        }
      }
  }
}

// ======== FC GEMM with fused-LN A-staging: relu + res, fp32 out ========
__global__ __launch_bounds__(256) void gemm_fc(const bf16_t* __restrict__ IN,
                                               const float* __restrict__ Psum,
                                               const float* __restrict__ Psq,
                                               const float* __restrict__ gam,
                                               const float* __restrict__ bet,
                                               const bf16_t* __restrict__ W,
                                               const float* __restrict__ bias,
                                               float* __restrict__ outf) {
  __shared__ __align__(16) bf16_t As[2][64 * 64];
  __shared__ __align__(16) bf16_t Bs[2][128 * 64];
  __shared__ float2 st[64];
  int tid = threadIdx.x;
  int w = tid >> 6, l = tid & 63;
  int m0 = blockIdx.x * 64, n0 = blockIdx.y * 128;
  int wr = w >> 1, wc = w & 1;
  int lc = l & 15, lg = l >> 4;
  int srow = l >> 3, scb = (l & 7) * 16;
  int cl = (l & 7) * 8;

  if (tid < 64) {
    int gr = m0 + tid;
    float s = 0.f, q = 0.f;
#pragma unroll
    for (int c = 0; c < 16; c++) {
      s += Psum[(size_t)gr * 16 + c];
      q += Psq[(size_t)gr * 16 + c];
    }
    float mean = s * (1.f / 512.f);
    float inv = rsqrtf(q * (1.f / 512.f) - mean * mean + 1e-5f);
    st[tid] = make_float2(mean, inv);
  }
  __syncthreads();

  int row0 = w * 8 + srow, row1 = row0 + 32;
  int csw = (scb ^ ((row0 & 7) << 4)) >> 1;
  float2 mi0 = st[row0], mi1 = st[row1];
  bf16x8 h0, h1;

#define FC_ALOAD(K0)                                                              \
  do {                                                                            \
    h0 = *(const bf16x8*)&IN[(size_t)(m0 + row0) * CCH + (K0) + cl];              \
    h1 = *(const bf16x8*)&IN[(size_t)(m0 + row1) * CCH + (K0) + cl];              \
  } while (0)

#define FC_AWRITE(BI, K0)                                                         \
  do {                                                                            \
    float gv[8], bv[8];                                                           \
    *(float4*)&gv[0] = *(const float4*)(gam + (K0) + cl);                         \
    *(float4*)&gv[4] = *(const float4*)(gam + (K0) + cl + 4);                     \
    *(float4*)&bv[0] = *(const float4*)(bet + (K0) + cl);                         \
    *(float4*)&bv[4] = *(const float4*)(bet + (K0) + cl + 4);                     \
    bf16x8 o0, o1;                                                                \
    _Pragma("unroll") for (int j = 0; j < 8; j++) {                               \
      o0[j] = (bf16_t)(((float)h0[j] - mi0.x) * mi0.y * gv[j] + bv[j]);           \
      o1[j] = (bf16_t)(((float)h1[j] - mi1.x) * mi1.y * gv[j] + bv[j]);           \
    }                                                                             \
    *(bf16x8*)&As[BI][row0 * 64 + csw] = o0;                                      \
    *(bf16x8*)&As[BI][row1 * 64 + csw] = o1;                                      \
  } while (0)

  f32x4 acc[2][4];
#pragma unroll
  for (int i = 0; i < 2; i++)
#pragma unroll
    for (int j = 0; j < 4; j++) acc[i][j] = f32x4{0.f, 0.f, 0.f, 0.f};

  BSTAGE128(W, 0, 0);
  FC_ALOAD(0);
  FC_AWRITE(0, 0);
  __syncthreads();
  int cur = 0;
  for (int kk = 0; kk < 8; kk++) {
    if (kk < 7) { BSTAGE128(W, cur ^ 1, (kk + 1) * 64); FC_ALOAD((kk + 1) * 64); }
    GCOMP64(cur);
    if (kk < 7) FC_AWRITE(cur ^ 1, (kk + 1) * 64);
    __syncthreads();
    cur ^= 1;
  }

#pragma unroll
  for (int i = 0; i < 2; i++) {
    int mbase = m0 + wr * 32 + i * 16 + lg * 4;
#pragma unroll
    for (int j = 0; j < 4; j++) {
      int n = n0 + wc * 64 + j * 16 + lc;
      float bn = bias[n];
#pragma unroll
      for (int r = 0; r < 4; r++) {
        int m = mbase + r;
        float v2 = fmaxf(acc[i][j][r] + bn, 0.f) + (float)IN[(size_t)m * CCH + n];
        outf[(size_t)m * CCH + n] = v2;
      }
    }
  }
}

// ======== qkv with fused-LN A-staging: BM=32 BN=256, V transposed ========
__global__ __launch_bounds__(256) void qkv_kernel(const bf16_t* __restrict__ IN,
                                                  const float* __restrict__ Psum,
                                                  const float* __restrict__ Psq,
                                                  const float* __restrict__ gam,
                                                  const float* __restrict__ bet,
                                                  const bf16_t* __restrict__ Wqkv,
                                                  const float* __restrict__ bq,
                                                  const float* __restrict__ bk,
                                                  const float* __restrict__ bv,
                                                  bf16_t* __restrict__ QB,
                                                  bf16_t* __restrict__ KB,
                                                  bf16_t* __restrict__ VT) {
  __shared__ __align__(16) bf16_t As[2][32 * 64];
  __shared__ __align__(16) bf16_t Bs[2][256 * 64];
  __shared__ float2 st[32];
  int tid = threadIdx.x;
  int w = tid >> 6, l = tid & 63;
  int m0 = blockIdx.x * 32, n0 = blockIdx.y * 256;
  int sec = n0 >> 9;
  int lc = l & 15, lg = l >> 4;
  int srow = l >> 3, scb = (l & 7) * 16;
  int cl = (l & 7) * 8;

  if (tid < 32) {
    int gr = m0 + tid;
    float s = 0.f, q = 0.f;
#pragma unroll
    for (int c = 0; c < 16; c++) {
      s += Psum[(size_t)gr * 16 + c];
      q += Psq[(size_t)gr * 16 + c];
    }
    float mean = s * (1.f / 512.f);
    float inv = rsqrtf(q * (1.f / 512.f) - mean * mean + 1e-5f);
    st[tid] = make_float2(mean, inv);
  }
  __syncthreads();

  int row0 = w * 8 + srow;
  int csw = (scb ^ ((row0 & 7) << 4)) >> 1;
  float2 mi = st[row0];
  bf16x8 hq;

#define QKV_ALOAD(K0) hq = *(const bf16x8*)&IN[(size_t)(m0 + row0) * CCH + (K0) + cl]

#define QKV_AWRITE(BI, K0)                                                        \
  do {                                                                            \
    float gv[8], bv[8];                                                           \
    *(float4*)&gv[0] = *(const float4*)(gam + (K0) + cl);                         \
    *(float4*)&gv[4] = *(const float4*)(gam + (K0) + cl + 4);                     \
    *(float4*)&bv[0] = *(const float4*)(bet + (K0) + cl);                         \
    *(float4*)&bv[4] = *(const float4*)(bet + (K0) + cl + 4);                     \
    bf16x8 o;                                                                     \
    _Pragma("unroll") for (int j = 0; j < 8; j++)                                 \
      o[j] = (bf16_t)(((float)hq[j] - mi.x) * mi.y * gv[j] + bv[j]);              \
    *(bf16x8*)&As[BI][row0 * 64 + csw] = o;                                       \
  } while (0)

#define QKV_BSTAGE(BI, K0)                                                        \
  _Pragma("unroll") for (int cc = 0; cc < 8; cc++) {                              \
    int row_ = cc * 32 + w * 8 + srow;                                            \
    int off_ = (scb ^ ((row_ & 7) << 4)) >> 1;                                    \
    gload_lds16(Wqkv + (size_t)(n0 + row_) * CCH + (K0) + off_,                   \
                &Bs[BI][(cc * 32 + w * 8) * 64]);                                 \
  }

  f32x4 acc[2][4];
#pragma unroll
  for (int i = 0; i < 2; i++)
#pragma unroll
    for (int j = 0; j < 4; j++) acc[i][j] = f32x4{0.f, 0.f, 0.f, 0.f};

  QKV_BSTAGE(0, 0);
  QKV_ALOAD(0);
  QKV_AWRITE(0, 0);
  __syncthreads();
  int cur = 0;
  for (int kk = 0; kk < 8; kk++) {
    if (kk < 7) { QKV_BSTAGE(cur ^ 1, (kk + 1) * 64); QKV_ALOAD((kk + 1) * 64); }
    __builtin_amdgcn_s_setprio(1);
#pragma unroll
    for (int ks = 0; ks < 2; ks++) {
      bf16x8 fa[2], fb[4];
#pragma unroll
      for (int i = 0; i < 2; i++) {
        int ra = i * 16 + lc;
        fa[i] = *(const bf16x8*)&As[cur][ra * 64 +
                 (((ks * 64 + lg * 16) ^ ((ra & 7) << 4)) >> 1)];
      }
#pragma unroll
      for (int j = 0; j < 4; j++) {
        int rb = w * 64 + j * 16 + lc;
        fb[j] = *(const bf16x8*)&Bs[cur][rb * 64 +
                 (((ks * 64 + lg * 16) ^ ((rb & 7) << 4)) >> 1)];
      }
#pragma unroll
      for (int i = 0; i < 2; i++)
#pragma unroll
        for (int j = 0; j < 4; j++)
          acc[i][j] = __builtin_amdgcn_mfma_f32_16x16x32_bf16(fa[i], fb[j], acc[i][j], 0, 0, 0);
    }
    __builtin_amdgcn_s_setprio(0);
    if (kk < 7) QKV_AWRITE(cur ^ 1, (kk + 1) * 64);
    __syncthreads();
    cur ^= 1;
  }

  const float* bp = (sec == 0) ? bq : (sec == 1) ? bk : bv;
#pragma unroll
  for (int i = 0; i < 2; i++) {
    int mbase = m0 + i * 16 + lg * 4;
#pragma unroll
    for (int j = 0; j < 4; j++) {
      int n = n0 + w * 64 + j * 16 + lc;
      int nl = n & 511;
      float bn = bp[nl];
      if (sec < 2) {
        bf16_t* ob = (sec == 0) ? QB : KB;
#pragma unroll
        for (int r = 0; r < 4; r++)
          ob[(size_t)(mbase + r) * CCH + nl] = (bf16_t)(acc[i][j][r] + bn);
      } else {
        int h = nl >> 6, d = nl & 63;
        int b = mbase >> 10, lpos = mbase & 1023;
        bf16x4 t;
#pragma unroll
        for (int r = 0; r < 4; r++) t[r] = (bf16_t)(acc[i][j][r] + bn);
        *(bf16x4*)&VT[(((size_t)(b * 8 + h) * 64 + d) * L_SEQ) + lpos] = t;
      }
    }
  }
}

// ---------------- flash attention (QBLK=128, dbuf K/V, setprio) ----------------
#define ATT_STAGE(BI, KC)                                                         \
  do {                                                                            \
    _Pragma("unroll") for (int r = 0; r < 2; r++) {                               \
      int row = r * 32 + w * 8 + srow;                                            \
      int sc = (scb ^ ((row & 7) << 4)) >> 1;                                     \
      int key = (KC) * 64 + row;                                                  \
      gload_lds16(K + ((size_t)(b * L_SEQ + key) * CCH + h * 64 + sc),            \
                  &Ks[BI][(r * 32 + w * 8) * 64]);                                \
      gload_lds16(VT + (((size_t)(b * 8 + h) * 64 + row) * L_SEQ + (KC) * 64 + sc),\
                  &Vs[BI][(r * 32 + w * 8) * 64]);                                \
    }                                                                             \
  } while (0)

__global__ __launch_bounds__(256) void attn_kernel(const bf16_t* __restrict__ Q,
                                                   const bf16_t* __restrict__ K,
                                                   const bf16_t* __restrict__ VT,
                                                   const float* __restrict__ mask,
                                                   bf16_t* __restrict__ O) {
  __shared__ __align__(16) bf16_t Ks[2][64 * 64];
  __shared__ __align__(16) bf16_t Vs[2][64 * 64];
  __shared__ __align__(16) bf16_t Pl[4][16 * 64];
  int tid = threadIdx.x;
  int w = tid >> 6, l = tid & 63;
  int bid = blockIdx.x;
  int sw = (bid & 7) * 64 + (bid >> 3);
  int qb = sw & 7, h = (sw >> 3) & 7, b = sw >> 6;
  int lg = l >> 4, lc = l & 15;

  bf16x8 qf[2][2];
#pragma unroll
  for (int s = 0; s < 2; s++) {
    int qrow = qb * 128 + s * 64 + w * 16 + lc;
    const bf16_t* qptr = Q + ((size_t)(b * L_SEQ + qrow) * CCH + h * 64);
    qf[s][0] = *(const bf16x8*)(qptr + lg * 8);
    qf[s][1] = *(const bf16x8*)(qptr + 32 + lg * 8);
  }

  f32x4 oacc[2][4];
  float psl[2][4];
#pragma unroll
  for (int s = 0; s < 2; s++)
#pragma unroll
    for (int nf = 0; nf < 4; nf++) {
      oacc[s][nf] = f32x4{0.f, 0.f, 0.f, 0.f};
      psl[s][nf] = 0.f;
    }

  int srow = l >> 3;
  int scb = (l & 7) * 16;

  ATT_STAGE(0, 0);
  __syncthreads();
  int cur = 0;
  for (int kc = 0; kc < 16; kc++) {
    if (kc < 15) ATT_STAGE(cur ^ 1, kc + 1);

    float mv[4];
#pragma unroll
    for (int kf = 0; kf < 4; kf++) mv[kf] = mask[b * L_SEQ + kc * 64 + kf * 16 + lc];

#pragma unroll
    for (int s = 0; s < 2; s++) {
      f32x4 sacc[4];
#pragma unroll
      for (int kf = 0; kf < 4; kf++) sacc[kf] = f32x4{0.f, 0.f, 0.f, 0.f};
      __builtin_amdgcn_s_setprio(1);
#pragma unroll
      for (int kf = 0; kf < 4; kf++) {
        int row = kf * 16 + lc;
        int sx = (row & 7) << 4;
        const bf16_t* kr = &Ks[cur][row * 64];
        bf16x8 b0 = *(const bf16x8*)(kr + (((lg * 16) ^ sx) >> 1));
        sacc[kf] = __builtin_amdgcn_mfma_f32_16x16x32_bf16(qf[s][0], b0, sacc[kf], 0, 0, 0);
        bf16x8 b1 = *(const bf16x8*)(kr + (((64 + lg * 16) ^ sx) >> 1));
        sacc[kf] = __builtin_amdgcn_mfma_f32_16x16x32_bf16(qf[s][1], b1, sacc[kf], 0, 0, 0);
      }
      __builtin_amdgcn_s_setprio(0);

#pragma unroll
      for (int kf = 0; kf < 4; kf++) {
        float mneg = (1.f - mv[kf]) * (-1e30f);
        float msc = 0.125f * mv[kf];
#pragma unroll
        for (int j = 0; j < 4; j++) {
          float p = __expf(sacc[kf][j] * msc + mneg);
          psl[s][j] += p;
          int q = lg * 4 + j;
          int cb = (kf * 32 + lc * 2) ^ ((q & 7) << 4);
          Pl[w][(q * 128 + cb) >> 1] = (bf16_t)p;
        }
      }

      int sp = (lc & 7) << 4;
      bf16x8 pa0 = *(const bf16x8*)&Pl[w][(lc * 128 + ((lg * 16) ^ sp)) >> 1];
      bf16x8 pa1 = *(const bf16x8*)&Pl[w][(lc * 128 + ((64 + lg * 16) ^ sp)) >> 1];
      __builtin_amdgcn_s_setprio(1);
#pragma unroll
      for (int nf = 0; nf < 4; nf++) {
        int d = nf * 16 + lc;
        int sx = (d & 7) << 4;
        const bf16_t* vr = &Vs[cur][d * 64];
        bf16x8 vb0 = *(const bf16x8*)(vr + (((lg * 16) ^ sx) >> 1));
        oacc[s][nf] = __builtin_amdgcn_mfma_f32_16x16x32_bf16(pa0, vb0, oacc[s][nf], 0, 0, 0);
        bf16x8 vb1 = *(const bf16x8*)(vr + (((64 + lg * 16) ^ sx) >> 1));
        oacc[s][nf] = __builtin_amdgcn_mfma_f32_16x16x32_bf16(pa1, vb1, oacc[s][nf], 0, 0, 0);
      }
      __builtin_amdgcn_s_setprio(0);
    }
    __syncthreads();
    cur ^= 1;
  }

#pragma unroll
  for (int off = 1; off < 16; off <<= 1)
#pragma unroll
    for (int s = 0; s < 2; s++)
#pragma unroll
      for (int j = 0; j < 4; j++) psl[s][j] += __shfl_xor(psl[s][j], off);

#pragma unroll
  for (int s = 0; s < 2; s++)
#pragma unroll
    for (int j = 0; j < 4; j++) {
      float is = 1.0f / psl[s][j];
      int r = qb * 128 + s * 64 + w * 16 + lg * 4 + j;
      bf16_t* op = O + ((size_t)(b * L_SEQ + r) * CCH + h * 64);
#pragma unroll
      for (int nf = 0; nf < 4; nf++) op[nf * 16 + lc] = (bf16_t)(oacc[s][nf][j] * is);
    }
}

// ---------------- launcher ----------------
extern "C" void kernel_launch(void* const* d_in, const int* in_sizes, int n_in,
                              void* d_out, int out_size, void* d_ws, size_t ws_size,
                              hipStream_t stream) {
  const float* x = (const float*)d_in[0];
  const float* mask = (const float*)d_in[1];
  const float* dw_w = (const float*)d_in[2];
  const float* dw_b = (const float*)d_in[3];
  const float* pw_w = (const float*)d_in[4];
  const float* pw_b = (const float*)d_in[5];
  const float* ln_conv_g = (const float*)d_in[6];
  const float* ln_conv_b = (const float*)d_in[7];
  const float* Wq = (const float*)d_in[8];  const float* bq = (const float*)d_in[9];
  const float* Wk = (const float*)d_in[10]; const float* bk = (const float*)d_in[11];
  const float* Wv = (const float*)d_in[12]; const float* bv = (const float*)d_in[13];
  const float* Wo = (const float*)d_in[14]; const float* bo = (const float*)d_in[15];
  const float* ln_att_g = (const float*)d_in[16]; const float* ln_att_b = (const float*)d_in[17];
  const float* Wf = (const float*)d_in[18]; const float* bfc = (const float*)d_in[19];
  const float* ln_fc_g = (const float*)d_in[20]; const float* ln_fc_b = (const float*)d_in[21];

  char* ws = (char*)d_ws;
  bf16_t* ABF  = (bf16_t*)(ws);                      // 8 MiB (attn out)
  bf16_t* QB   = (bf16_t*)(ws + (8u << 20));         // 8 MiB
  bf16_t* KB   = (bf16_t*)(ws + (16u << 20));        // 8 MiB
  bf16_t* VT   = (bf16_t*)(ws + (24u << 20));        // 8 MiB  [b][h][d][key]
  char*   wb   = ws + (32u << 20);
  bf16_t* WPW  = (bf16_t*)(wb);                      // 2 MiB
  bf16_t* WQKV = (bf16_t*)(wb + (2u << 20));         // 1.5 MiB
  bf16_t* WOB  = (bf16_t*)(wb + 3584u * 1024);       // 0.5 MiB
  bf16_t* WFB  = (bf16_t*)(wb + (4u << 20));         // 0.5 MiB
  float*  WT   = (float*)(wb + 4608u * 1024);        // 56 KiB
  float*  PsA  = (float*)(ws + (38u << 20));         // 512K sum + 512K sq
  float*  PsAq = PsA + 131072;
  float*  PsB  = (float*)(ws + (39u << 20));
  float*  PsBq = PsB + 131072;
  bf16_t* OUTA = (bf16_t*)(ws + (40u << 20));        // 8 MiB
  bf16_t* OUTB = (bf16_t*)(ws + (48u << 20));        // 8 MiB

  prep_kernel<<<15416, 256, 0, stream>>>(x, pw_w, Wq, Wk, Wv, Wo, Wf, dw_w,
                                         WPW, WQKV, WOB, WFB, WT,
                                         OUTA, PsA, PsAq);

  dim3 ggrid(128, 4);
  // conv stages with ping-pong OUT/stats: A->B->A->B->A
  bf16_t* ib[5] = {OUTA, OUTB, OUTA, OUTB, OUTA};
  float*  ps[5] = {PsA, PsB, PsA, PsB, PsA};
  float*  pq[5] = {PsAq, PsBq, PsAq, PsBq, PsAq};
  for (int i = 0; i < 4; i++) {
    gemm_conv<<<ggrid, 256, 0, stream>>>(ib[i], ps[i], pq[i],
                                         ln_conv_g + i * 512, ln_conv_b + i * 512,
                                         WT + i * 3584, dw_b + i * 512,
                                         WPW + i * 262144, pw_b + i * 512,
                                         ib[i + 1], ps[i + 1], pq[i + 1]);
  }
  // attention: LN fused into qkv A-staging (reads OUTA/PsA)
  qkv_kernel<<<dim3(256, 6), 256, 0, stream>>>(OUTA, PsA, PsAq, ln_att_g, ln_att_b,
                                               WQKV, bq, bk, bv, QB, KB, VT);
  attn_kernel<<<512, 256, 0, stream>>>(QB, KB, VT, mask, ABF);
  gemm_wo<<<ggrid, 256, 0, stream>>>(ABF, WOB, bo, OUTA, OUTB, PsB, PsBq);
  // FC: LN fused (reads OUTB/PsB), writes fp32 d_out
  gemm_fc<<<ggrid, 256, 0, stream>>>(OUTB, PsB, PsBq, ln_fc_g, ln_fc_b,
                                     WFB, bfc, (float*)d_out);
}